// Round 1
// baseline (3130.158 us; speedup 1.0000x reference)
//
#include <hip/hip_runtime.h>

typedef __attribute__((ext_vector_type(8))) short bf16x8;
typedef __attribute__((ext_vector_type(4))) float f32x4;
typedef __attribute__((ext_vector_type(4))) unsigned short us4;

static __device__ __forceinline__ float bf2f(unsigned short u) {
    union { unsigned int i; float f; } cv; cv.i = ((unsigned int)u) << 16;
    return cv.f;
}
static __device__ __forceinline__ unsigned short f2bf(float f) {
    union { float f; unsigned int i; } cv; cv.f = f;
    unsigned int x = cv.i;
    unsigned int lsb = (x >> 16) & 1u;
    x += 0x7fffu + lsb;
    return (unsigned short)(x >> 16);
}

// ---------------- degree ----------------
__global__ __launch_bounds__(256) void k_deg(const int* __restrict__ dst,
                                             float* __restrict__ cnt, int E) {
    int i = blockIdx.x * 256 + threadIdx.x;
    if (i < E) atomicAdd(&cnt[dst[i]], 1.0f);
}

// ---------------- scatter-add, fp32 source ----------------
__global__ __launch_bounds__(256) void k_scatter_f32(const float* __restrict__ x,
                                                     const int* __restrict__ src,
                                                     const int* __restrict__ dst,
                                                     float* __restrict__ agg, int E) {
    int gw = (int)((blockIdx.x * 256 + threadIdx.x) >> 6);
    if (gw >= E) return;
    int l = threadIdx.x & 63;
    int s = src[gw], d = dst[gw];
    f32x4 v = *((const f32x4*)(x + (size_t)s * 256) + l);
    float* ap = agg + (size_t)d * 256 + l * 4;
    atomicAdd(ap + 0, v.x);
    atomicAdd(ap + 1, v.y);
    atomicAdd(ap + 2, v.z);
    atomicAdd(ap + 3, v.w);
}

// ---------------- scatter-add, bf16 source ----------------
__global__ __launch_bounds__(256) void k_scatter_bf16(const unsigned short* __restrict__ x,
                                                      const int* __restrict__ src,
                                                      const int* __restrict__ dst,
                                                      float* __restrict__ agg, int E) {
    int gw = (int)((blockIdx.x * 256 + threadIdx.x) >> 6);
    if (gw >= E) return;
    int l = threadIdx.x & 63;
    int s = src[gw], d = dst[gw];
    us4 v = *((const us4*)(x + (size_t)s * 256) + l);
    float* ap = agg + (size_t)d * 256 + l * 4;
    atomicAdd(ap + 0, bf2f(v.x));
    atomicAdd(ap + 1, bf2f(v.y));
    atomicAdd(ap + 2, bf2f(v.z));
    atomicAdd(ap + 3, bf2f(v.w));
}

// ---------------- weight conversion: Wc[n][k] = (k<256 ? Wl[n][k] : Wr[n][k-256]) ----------------
__global__ __launch_bounds__(256) void k_convw(const float* __restrict__ Wl,
                                               const float* __restrict__ Wr,
                                               const float* __restrict__ fcW,
                                               unsigned short* __restrict__ Wc1,
                                               unsigned short* __restrict__ Wc2,
                                               unsigned short* __restrict__ fcWb) {
    int idx = blockIdx.x * 256 + threadIdx.x;
    if (idx < 2 * 256 * 512) {
        int layer = idx >> 17;
        int r = idx & ((1 << 17) - 1);
        int n = r >> 9;
        int k = r & 511;
        int base = layer * 3 * 256 * 256;  // Wl[layer][rel=0]
        float v = (k < 256) ? Wl[base + n * 256 + k] : Wr[base + n * 256 + (k - 256)];
        (layer ? Wc2 : Wc1)[n * 512 + k] = f2bf(v);
    } else {
        int i = idx - 2 * 256 * 512;
        if (i < 128 * 256) fcWb[i] = f2bf(fcW[i]);
    }
}

// ---------------- layer GEMM: out = relu([agg*rinv | xs] @ Wc^T + bias), bf16 out ----------------
// block = 256 threads (4 waves), BM=64, BN=256 (full), K=512, k-step 32.
__global__ __launch_bounds__(256) void k_sage_gemm(const float* __restrict__ agg,
                                                   const float* __restrict__ cnt,
                                                   const void* __restrict__ xs, const int xs_bf16,
                                                   const unsigned short* __restrict__ Wc,
                                                   const float* __restrict__ bias,
                                                   unsigned short* __restrict__ out) {
    __shared__ __align__(16) unsigned short Alds[64][56];
    __shared__ __align__(16) unsigned short Blds[256][56];
    const int t = threadIdx.x;
    const int row0 = blockIdx.x * 64;
    const int w = t >> 6, l = t & 63;
    const int lrow = l & 15, lk = (l >> 4) << 3;

    f32x4 acc[16];
#pragma unroll
    for (int i = 0; i < 16; ++i)
#pragma unroll
        for (int j = 0; j < 4; ++j) acc[i][j] = 0.0f;

    const int ar = t >> 2;          // staging row 0..63
    const int ak = (t & 3) << 3;    // staging k offset 0,8,16,24
    const float rinv = 1.0f / fmaxf(cnt[row0 + ar], 1.0f);

    for (int k0 = 0; k0 < 512; k0 += 32) {
        // stage A (64x32), converting to bf16; mean = agg * rinv folded in
        {
            union { bf16x8 v; unsigned short u[8]; } tmp;
            if (k0 < 256) {
                const f32x4* p = (const f32x4*)(agg + (size_t)(row0 + ar) * 256 + k0 + ak);
                f32x4 u0 = p[0], u1 = p[1];
                tmp.u[0] = f2bf(u0.x * rinv); tmp.u[1] = f2bf(u0.y * rinv);
                tmp.u[2] = f2bf(u0.z * rinv); tmp.u[3] = f2bf(u0.w * rinv);
                tmp.u[4] = f2bf(u1.x * rinv); tmp.u[5] = f2bf(u1.y * rinv);
                tmp.u[6] = f2bf(u1.z * rinv); tmp.u[7] = f2bf(u1.w * rinv);
            } else {
                int kk = (k0 - 256) + ak;
                if (xs_bf16) {
                    tmp.v = *(const bf16x8*)((const unsigned short*)xs + (size_t)(row0 + ar) * 256 + kk);
                } else {
                    const f32x4* p = (const f32x4*)((const float*)xs + (size_t)(row0 + ar) * 256 + kk);
                    f32x4 u0 = p[0], u1 = p[1];
                    tmp.u[0] = f2bf(u0.x); tmp.u[1] = f2bf(u0.y);
                    tmp.u[2] = f2bf(u0.z); tmp.u[3] = f2bf(u0.w);
                    tmp.u[4] = f2bf(u1.x); tmp.u[5] = f2bf(u1.y);
                    tmp.u[6] = f2bf(u1.z); tmp.u[7] = f2bf(u1.w);
                }
            }
            *(bf16x8*)(&Alds[ar][ak]) = tmp.v;
        }
        // stage B^T (256 n-rows x 32 k): Blds[n][kk] = Wc[n][k0+kk]
#pragma unroll
        for (int i = 0; i < 4; ++i) {
            int c = t + 256 * i;          // 0..1023 chunks of 8
            int n = c >> 2, kk = (c & 3) << 3;
            *(bf16x8*)(&Blds[n][kk]) = *(const bf16x8*)(Wc + n * 512 + k0 + kk);
        }
        __syncthreads();
        bf16x8 a = *(const bf16x8*)(&Alds[w * 16 + lrow][lk]);
#pragma unroll
        for (int nt = 0; nt < 16; ++nt) {
            bf16x8 b = *(const bf16x8*)(&Blds[nt * 16 + lrow][lk]);
            acc[nt] = __builtin_amdgcn_mfma_f32_16x16x32_bf16(a, b, acc[nt], 0, 0, 0);
        }
        __syncthreads();
    }
    // epilogue: D mapping col=lane&15, row=(lane>>4)*4+reg
#pragma unroll
    for (int nt = 0; nt < 16; ++nt) {
        int col = nt * 16 + lrow;
        float bb = bias[col];
#pragma unroll
        for (int r = 0; r < 4; ++r) {
            int grow = row0 + w * 16 + (l >> 4) * 4 + r;
            float v = acc[nt][r] + bb;
            v = fmaxf(v, 0.0f);
            out[(size_t)grow * 256 + col] = f2bf(v);
        }
    }
}

// ---------------- fc GEMM: out = g @ fcW^T + fcb, fp32 out; g lives in the SAME buffer as out ----------------
__global__ __launch_bounds__(256) void k_fc_gemm(const unsigned short* __restrict__ g,
                                                 const unsigned short* __restrict__ fcWb,
                                                 const float* __restrict__ fcb,
                                                 float* __restrict__ out) {
    __shared__ __align__(16) unsigned short Alds[64][56];
    __shared__ __align__(16) unsigned short Blds[128][56];
    const int t = threadIdx.x;
    const int row0 = blockIdx.x * 64;
    const int w = t >> 6, l = t & 63;
    const int lrow = l & 15, lk = (l >> 4) << 3;

    f32x4 acc[8];
#pragma unroll
    for (int i = 0; i < 8; ++i)
#pragma unroll
        for (int j = 0; j < 4; ++j) acc[i][j] = 0.0f;

    const int ar = t >> 2;
    const int ak = (t & 3) << 3;

    for (int k0 = 0; k0 < 256; k0 += 32) {
        *(bf16x8*)(&Alds[ar][ak]) =
            *(const bf16x8*)(g + (size_t)(row0 + ar) * 256 + k0 + ak);
#pragma unroll
        for (int i = 0; i < 2; ++i) {
            int c = t + 256 * i;          // 0..511
            int n = c >> 2, kk = (c & 3) << 3;
            *(bf16x8*)(&Blds[n][kk]) = *(const bf16x8*)(fcWb + n * 256 + k0 + kk);
        }
        __syncthreads();
        bf16x8 a = *(const bf16x8*)(&Alds[w * 16 + lrow][lk]);
#pragma unroll
        for (int nt = 0; nt < 8; ++nt) {
            bf16x8 b = *(const bf16x8*)(&Blds[nt * 16 + lrow][lk]);
            acc[nt] = __builtin_amdgcn_mfma_f32_16x16x32_bf16(a, b, acc[nt], 0, 0, 0);
        }
        __syncthreads();
    }
    // all global reads of this block's g rows are complete; safe to overwrite same bytes
#pragma unroll
    for (int nt = 0; nt < 8; ++nt) {
        int col = nt * 16 + lrow;
        float bb = fcb[col];
#pragma unroll
        for (int r = 0; r < 4; ++r) {
            int grow = row0 + w * 16 + (l >> 4) * 4 + r;
            out[(size_t)grow * 128 + col] = acc[nt][r] + bb;
        }
    }
}

extern "C" void kernel_launch(void* const* d_in, const int* in_sizes, int n_in,
                              void* d_out, int out_size, void* d_ws, size_t ws_size,
                              hipStream_t stream) {
    const float* x_word = (const float*)d_in[0];
    const float* Wl  = (const float*)d_in[3];
    const float* bl  = (const float*)d_in[4];
    const float* Wr  = (const float*)d_in[5];
    const float* fcW = (const float*)d_in[6];
    const float* fcb = (const float*)d_in[7];
    const int* src = (const int*)d_in[8];
    const int* dst = (const int*)d_in[9];

    const int M = in_sizes[0] / 256;   // 200000 (divisible by 64)
    const int E = in_sizes[8];         // 400000

    char* ws = (char*)d_ws;
    size_t off = 0;
    auto alloc = [&](size_t bytes) {
        void* p = ws + off;
        off = (off + bytes + 255) & ~(size_t)255;
        return p;
    };
    float* cnt  = (float*)alloc((size_t)M * 4);
    float* aggb = (float*)alloc((size_t)M * 256 * 4);
    unsigned short* h    = (unsigned short*)alloc((size_t)M * 256 * 2);
    unsigned short* Wc1  = (unsigned short*)alloc(256 * 512 * 2);
    unsigned short* Wc2  = (unsigned short*)alloc(256 * 512 * 2);
    unsigned short* fcWb = (unsigned short*)alloc(128 * 256 * 2);

    unsigned short* g = (unsigned short*)d_out;  // bf16 g staged inside d_out (same byte count)

    hipMemsetAsync(cnt, 0, (size_t)M * 4, stream);
    hipMemsetAsync(aggb, 0, (size_t)M * 256 * 4, stream);
    k_convw<<<1152, 256, 0, stream>>>(Wl, Wr, fcW, Wc1, Wc2, fcWb);
    k_deg<<<(E + 255) / 256, 256, 0, stream>>>(dst, cnt, E);

    // Layer 1 (word<-word over dep edges)
    k_scatter_f32<<<E / 4, 256, 0, stream>>>(x_word, src, dst, aggb, E);
    k_sage_gemm<<<M / 64, 256, 0, stream>>>(aggb, cnt, (const void*)x_word, 0, Wc1, bl, h);

    // Layer 2
    hipMemsetAsync(aggb, 0, (size_t)M * 256 * 4, stream);
    k_scatter_bf16<<<E / 4, 256, 0, stream>>>(h, src, dst, aggb, E);
    k_sage_gemm<<<M / 64, 256, 0, stream>>>(aggb, cnt, (const void*)h, 1, Wc2, bl + 3 * 256, g);

    // fc head: reads g (bf16) from d_out, overwrites same bytes with fp32 out
    k_fc_gemm<<<M / 64, 256, 0, stream>>>(g, fcWb, fcb, (float*)d_out);
}

// Round 2
// 587.147 us; speedup vs baseline: 5.3311x; 5.3311x over previous
//
#include <hip/hip_runtime.h>

typedef __attribute__((ext_vector_type(8))) short bf16x8;
typedef __attribute__((ext_vector_type(4))) float f32x4;
typedef __attribute__((ext_vector_type(4))) unsigned short us4;

static __device__ __forceinline__ float bf2f(unsigned short u) {
    union { unsigned int i; float f; } cv; cv.i = ((unsigned int)u) << 16;
    return cv.f;
}
static __device__ __forceinline__ unsigned short f2bf(float f) {
    union { float f; unsigned int i; } cv; cv.f = f;
    unsigned int x = cv.i;
    unsigned int lsb = (x >> 16) & 1u;
    x += 0x7fffu + lsb;
    return (unsigned short)(x >> 16);
}

// ---------------- CSR build ----------------
__global__ __launch_bounds__(256) void k_hist(const int* __restrict__ dst,
                                              int* __restrict__ cnt, int E) {
    int i = blockIdx.x * 256 + threadIdx.x;
    if (i < E) atomicAdd(&cnt[dst[i]], 1);
}

// block b sums cnt[b*1024 .. b*1024+1023] -> bsum[b]
__global__ __launch_bounds__(256) void k_bsum(const int* __restrict__ cnt,
                                              int* __restrict__ bsum, int M) {
    __shared__ int sm[256];
    int t = threadIdx.x;
    int base = blockIdx.x * 1024 + t * 4;
    int s = 0;
#pragma unroll
    for (int j = 0; j < 4; ++j) {
        int i = base + j;
        if (i < M) s += cnt[i];
    }
    sm[t] = s;
    __syncthreads();
    for (int off = 128; off; off >>= 1) {
        if (t < off) sm[t] += sm[t + off];
        __syncthreads();
    }
    if (t == 0) bsum[blockIdx.x] = sm[0];
}

// single thread: exclusive scan of bsum (NB ~ 196), and rowptr[M] = E
__global__ void k_scanb(int* __restrict__ bsum, int NB,
                        int* __restrict__ rowptr, int M, int E) {
    if (threadIdx.x == 0 && blockIdx.x == 0) {
        int run = 0;
        for (int b = 0; b < NB; ++b) {
            int v = bsum[b];
            bsum[b] = run;
            run += v;
        }
        rowptr[M] = E;
    }
}

// per-block exclusive scan over its 1024 counts, offset by bsum[b]; writes rowptr + cursor
__global__ __launch_bounds__(256) void k_rowptr(const int* __restrict__ cnt,
                                                const int* __restrict__ bsum,
                                                int* __restrict__ rowptr,
                                                int* __restrict__ cursor, int M) {
    __shared__ int sm[256];
    int t = threadIdx.x;
    int base = blockIdx.x * 1024 + t * 4;
    int c[4];
    int ts = 0;
#pragma unroll
    for (int j = 0; j < 4; ++j) {
        int i = base + j;
        c[j] = (i < M) ? cnt[i] : 0;
        ts += c[j];
    }
    sm[t] = ts;
    __syncthreads();
    for (int off = 1; off < 256; off <<= 1) {
        int v = (t >= off) ? sm[t - off] : 0;
        __syncthreads();
        sm[t] += v;
        __syncthreads();
    }
    int ex = bsum[blockIdx.x] + sm[t] - ts;   // exclusive prefix for this thread's chunk
#pragma unroll
    for (int j = 0; j < 4; ++j) {
        int i = base + j;
        if (i < M) {
            rowptr[i] = ex;
            cursor[i] = ex;
        }
        ex += c[j];
    }
}

__global__ __launch_bounds__(256) void k_place(const int* __restrict__ src,
                                               const int* __restrict__ dst,
                                               int* __restrict__ cursor,
                                               int* __restrict__ eidx, int E) {
    int i = blockIdx.x * 256 + threadIdx.x;
    if (i < E) {
        int slot = atomicAdd(&cursor[dst[i]], 1);
        eidx[slot] = src[i];
    }
}

// ---------------- f32 -> bf16 bulk convert ----------------
__global__ __launch_bounds__(256) void k_convx(const float* __restrict__ x,
                                               unsigned short* __restrict__ xb, int n8) {
    int i = blockIdx.x * 256 + threadIdx.x;
    if (i >= n8) return;
    const f32x4* p = (const f32x4*)(x + (size_t)i * 8);
    f32x4 u0 = p[0], u1 = p[1];
    union { bf16x8 v; unsigned short u[8]; } tmp;
    tmp.u[0] = f2bf(u0.x); tmp.u[1] = f2bf(u0.y);
    tmp.u[2] = f2bf(u0.z); tmp.u[3] = f2bf(u0.w);
    tmp.u[4] = f2bf(u1.x); tmp.u[5] = f2bf(u1.y);
    tmp.u[6] = f2bf(u1.z); tmp.u[7] = f2bf(u1.w);
    *(bf16x8*)(xb + (size_t)i * 8) = tmp.v;
}

// ---------------- pull aggregation: mean[r] = (1/deg) * sum_{e} xsrc[eidx[e]] ----------------
// one wave per dst row; lane l covers bf16 elements [l*4, l*4+4)
__global__ __launch_bounds__(256) void k_gather_mean(const unsigned short* __restrict__ xsrc,
                                                     const int* __restrict__ rowptr,
                                                     const int* __restrict__ eidx,
                                                     unsigned short* __restrict__ mean, int M) {
    int r = blockIdx.x * 4 + (threadIdx.x >> 6);
    if (r >= M) return;
    int l = threadIdx.x & 63;
    int s0 = rowptr[r], s1 = rowptr[r + 1];
    float a0 = 0.f, a1 = 0.f, a2 = 0.f, a3 = 0.f;
    for (int e = s0; e < s1; ++e) {
        int s = eidx[e];
        us4 v = *((const us4*)(xsrc + (size_t)s * 256) + l);
        a0 += bf2f(v.x); a1 += bf2f(v.y); a2 += bf2f(v.z); a3 += bf2f(v.w);
    }
    float rinv = (s1 > s0) ? 1.0f / (float)(s1 - s0) : 0.0f;  // isolated -> 0
    us4 o;
    o.x = f2bf(a0 * rinv); o.y = f2bf(a1 * rinv);
    o.z = f2bf(a2 * rinv); o.w = f2bf(a3 * rinv);
    *((us4*)(mean + (size_t)r * 256) + l) = o;
}

// ---------------- weight conversion: Wc[n][k] = (k<256 ? Wl[n][k] : Wr[n][k-256]) ----------------
__global__ __launch_bounds__(256) void k_convw(const float* __restrict__ Wl,
                                               const float* __restrict__ Wr,
                                               const float* __restrict__ fcW,
                                               unsigned short* __restrict__ Wc1,
                                               unsigned short* __restrict__ Wc2,
                                               unsigned short* __restrict__ fcWb) {
    int idx = blockIdx.x * 256 + threadIdx.x;
    if (idx < 2 * 256 * 512) {
        int layer = idx >> 17;
        int r = idx & ((1 << 17) - 1);
        int n = r >> 9;
        int k = r & 511;
        int base = layer * 3 * 256 * 256;  // Wl[layer][rel=0]
        float v = (k < 256) ? Wl[base + n * 256 + k] : Wr[base + n * 256 + (k - 256)];
        (layer ? Wc2 : Wc1)[n * 512 + k] = f2bf(v);
    } else {
        int i = idx - 2 * 256 * 512;
        if (i < 128 * 256) fcWb[i] = f2bf(fcW[i]);
    }
}

// ---------------- layer GEMM: out = relu([mean | xs] @ Wc^T + bias), bf16 out ----------------
// block = 256 threads (4 waves), BM=64, BN=256 (full), K=512, k-step 32.
__global__ __launch_bounds__(256) void k_sage_gemm(const unsigned short* __restrict__ meanb,
                                                   const unsigned short* __restrict__ xs,
                                                   const unsigned short* __restrict__ Wc,
                                                   const float* __restrict__ bias,
                                                   unsigned short* __restrict__ out) {
    __shared__ __align__(16) unsigned short Alds[64][56];
    __shared__ __align__(16) unsigned short Blds[256][56];
    const int t = threadIdx.x;
    const int row0 = blockIdx.x * 64;
    const int w = t >> 6, l = t & 63;
    const int lrow = l & 15, lk = (l >> 4) << 3;

    f32x4 acc[16];
#pragma unroll
    for (int i = 0; i < 16; ++i)
#pragma unroll
        for (int j = 0; j < 4; ++j) acc[i][j] = 0.0f;

    const int ar = t >> 2;          // staging row 0..63
    const int ak = (t & 3) << 3;    // staging k offset 0,8,16,24

    for (int k0 = 0; k0 < 512; k0 += 32) {
        // stage A (64x32) from bf16 mean / xs
        const unsigned short* abase = (k0 < 256)
            ? meanb + (size_t)(row0 + ar) * 256 + k0 + ak
            : xs + (size_t)(row0 + ar) * 256 + (k0 - 256) + ak;
        *(bf16x8*)(&Alds[ar][ak]) = *(const bf16x8*)abase;
        // stage B^T (256 n-rows x 32 k): Blds[n][kk] = Wc[n][k0+kk]
#pragma unroll
        for (int i = 0; i < 4; ++i) {
            int c = t + 256 * i;          // 0..1023 chunks of 8
            int n = c >> 2, kk = (c & 3) << 3;
            *(bf16x8*)(&Blds[n][kk]) = *(const bf16x8*)(Wc + n * 512 + k0 + kk);
        }
        __syncthreads();
        bf16x8 a = *(const bf16x8*)(&Alds[w * 16 + lrow][lk]);
#pragma unroll
        for (int nt = 0; nt < 16; ++nt) {
            bf16x8 b = *(const bf16x8*)(&Blds[nt * 16 + lrow][lk]);
            acc[nt] = __builtin_amdgcn_mfma_f32_16x16x32_bf16(a, b, acc[nt], 0, 0, 0);
        }
        __syncthreads();
    }
    // epilogue: D mapping col=lane&15, row=(lane>>4)*4+reg
#pragma unroll
    for (int nt = 0; nt < 16; ++nt) {
        int col = nt * 16 + lrow;
        float bb = bias[col];
#pragma unroll
        for (int r = 0; r < 4; ++r) {
            int grow = row0 + w * 16 + (l >> 4) * 4 + r;
            float v = acc[nt][r] + bb;
            v = fmaxf(v, 0.0f);
            out[(size_t)grow * 256 + col] = f2bf(v);
        }
    }
}

// ---------------- fc GEMM: out = g @ fcW^T + fcb, fp32 out; g lives in the SAME buffer as out ----------------
__global__ __launch_bounds__(256) void k_fc_gemm(const unsigned short* __restrict__ g,
                                                 const unsigned short* __restrict__ fcWb,
                                                 const float* __restrict__ fcb,
                                                 float* __restrict__ out) {
    __shared__ __align__(16) unsigned short Alds[64][56];
    __shared__ __align__(16) unsigned short Blds[128][56];
    const int t = threadIdx.x;
    const int row0 = blockIdx.x * 64;
    const int w = t >> 6, l = t & 63;
    const int lrow = l & 15, lk = (l >> 4) << 3;

    f32x4 acc[8];
#pragma unroll
    for (int i = 0; i < 8; ++i)
#pragma unroll
        for (int j = 0; j < 4; ++j) acc[i][j] = 0.0f;

    const int ar = t >> 2;
    const int ak = (t & 3) << 3;

    for (int k0 = 0; k0 < 256; k0 += 32) {
        *(bf16x8*)(&Alds[ar][ak]) =
            *(const bf16x8*)(g + (size_t)(row0 + ar) * 256 + k0 + ak);
#pragma unroll
        for (int i = 0; i < 2; ++i) {
            int c = t + 256 * i;          // 0..511
            int n = c >> 2, kk = (c & 3) << 3;
            *(bf16x8*)(&Blds[n][kk]) = *(const bf16x8*)(fcWb + n * 256 + k0 + kk);
        }
        __syncthreads();
        bf16x8 a = *(const bf16x8*)(&Alds[w * 16 + lrow][lk]);
#pragma unroll
        for (int nt = 0; nt < 8; ++nt) {
            bf16x8 b = *(const bf16x8*)(&Blds[nt * 16 + lrow][lk]);
            acc[nt] = __builtin_amdgcn_mfma_f32_16x16x32_bf16(a, b, acc[nt], 0, 0, 0);
        }
        __syncthreads();
    }
    // all global reads of this block's g rows are complete; safe to overwrite same bytes
#pragma unroll
    for (int nt = 0; nt < 8; ++nt) {
        int col = nt * 16 + lrow;
        float bb = fcb[col];
#pragma unroll
        for (int r = 0; r < 4; ++r) {
            int grow = row0 + w * 16 + (l >> 4) * 4 + r;
            out[(size_t)grow * 128 + col] = acc[nt][r] + bb;
        }
    }
}

extern "C" void kernel_launch(void* const* d_in, const int* in_sizes, int n_in,
                              void* d_out, int out_size, void* d_ws, size_t ws_size,
                              hipStream_t stream) {
    const float* x_word = (const float*)d_in[0];
    const float* Wl  = (const float*)d_in[3];
    const float* bl  = (const float*)d_in[4];
    const float* Wr  = (const float*)d_in[5];
    const float* fcW = (const float*)d_in[6];
    const float* fcb = (const float*)d_in[7];
    const int* src = (const int*)d_in[8];
    const int* dst = (const int*)d_in[9];

    const int M = in_sizes[0] / 256;   // 200000 (divisible by 64)
    const int E = in_sizes[8];         // 400000
    const int NB = (M + 1023) / 1024;  // scan blocks

    char* ws = (char*)d_ws;
    size_t off = 0;
    auto alloc = [&](size_t bytes) {
        void* p = ws + off;
        off = (off + bytes + 255) & ~(size_t)255;
        return p;
    };
    int* cnt_i  = (int*)alloc((size_t)M * 4);
    int* rowptr = (int*)alloc((size_t)(M + 1) * 4);
    int* cursor = (int*)alloc((size_t)M * 4);
    int* eidx   = (int*)alloc((size_t)E * 4);
    int* bsum   = (int*)alloc((size_t)NB * 4);
    unsigned short* xb    = (unsigned short*)alloc((size_t)M * 256 * 2);
    unsigned short* meanb = (unsigned short*)alloc((size_t)M * 256 * 2);
    unsigned short* h     = (unsigned short*)alloc((size_t)M * 256 * 2);
    unsigned short* Wc1   = (unsigned short*)alloc(256 * 512 * 2);
    unsigned short* Wc2   = (unsigned short*)alloc(256 * 512 * 2);
    unsigned short* fcWb  = (unsigned short*)alloc(128 * 256 * 2);

    unsigned short* g = (unsigned short*)d_out;  // bf16 g staged inside d_out (same byte count)

    // CSR build
    hipMemsetAsync(cnt_i, 0, (size_t)M * 4, stream);
    k_hist<<<(E + 255) / 256, 256, 0, stream>>>(dst, cnt_i, E);
    k_bsum<<<NB, 256, 0, stream>>>(cnt_i, bsum, M);
    k_scanb<<<1, 64, 0, stream>>>(bsum, NB, rowptr, M, E);
    k_rowptr<<<NB, 256, 0, stream>>>(cnt_i, bsum, rowptr, cursor, M);
    k_place<<<(E + 255) / 256, 256, 0, stream>>>(src, dst, cursor, eidx, E);

    // weights + x -> bf16
    k_convw<<<1152, 256, 0, stream>>>(Wl, Wr, fcW, Wc1, Wc2, fcWb);
    k_convx<<<(M * 256 / 8 + 255) / 256, 256, 0, stream>>>(x_word, xb, M * 256 / 8);

    // Layer 1 (word<-word over dep edges)
    k_gather_mean<<<(M + 3) / 4, 256, 0, stream>>>(xb, rowptr, eidx, meanb, M);
    k_sage_gemm<<<M / 64, 256, 0, stream>>>(meanb, xb, Wc1, bl, h);

    // Layer 2
    k_gather_mean<<<(M + 3) / 4, 256, 0, stream>>>(h, rowptr, eidx, meanb, M);
    k_sage_gemm<<<M / 64, 256, 0, stream>>>(meanb, h, Wc2, bl + 3 * 256, g);

    // fc head: reads g (bf16) from d_out, overwrites same bytes with fp32 out
    k_fc_gemm<<<M / 64, 256, 0, stream>>>(g, fcWb, fcb, (float*)d_out);
}